// Round 2
// baseline (561.583 us; speedup 1.0000x reference)
//
#include <hip/hip_runtime.h>

// Problem constants (from reference):
//   bpe_features [B, LAYERS, L, D] fp32
//   layer_w      [LAYERS]          fp32
//   word_ids     [B, L]            int32 (word j covers tokens 2j, 2j+1)
//   out          [B, MAX_WORDS, D] fp32
#define BB 16
#define LAYERS 13
#define LL 512
#define DD 1024
#define WW 256        // MAX_WORDS
#define WPB 4         // words per block
#define TPB (2*WPB)   // tokens per block = 8
#define GPB (WW/WPB)  // word-groups per batch = 64

typedef float f32x4 __attribute__((ext_vector_type(4)));

// One block per (b, group-of-4-words). 256 threads, each owns one float4
// slice of D. Per layer the block reads a CONTIGUOUS 32 KB span (8 tokens x
// 4 KB) instead of the previous 8 KB, and the grid drops 4096 -> 1024 blocks:
// theory is the previous kernel's 0.85 TB/s came from a fragmented DRAM
// request stream (tiny per-block footprints, 2 MB jumps every 8 KB), not
// from load serialization. Loads are plain (cached) -- nt retained only on
// the store; the 6.3 TB/s copy ceiling was measured without nt loads.
//
// Numerics identical to the verified kernel: membership scales (0/1) and
// 1/count factor out of the layer reduction, so the inner loop is
// unconditional independent float4 loads + FMAs.
__global__ __launch_bounds__(256) void MorphologicalTagger_13657996001460_kernel(
    const float* __restrict__ bpe,       // [BB, LAYERS, LL, DD]
    const float* __restrict__ layer_w,   // [LAYERS]
    const int*   __restrict__ word_ids,  // [BB, LL]
    float*       __restrict__ out)       // [BB, WW, DD]
{
    const int blk = blockIdx.x;
    const int b   = blk >> 6;            // / GPB
    const int jg  = blk & (GPB - 1);     // word group within batch
    const int j0  = jg * WPB;            // first word of group
    const int tid = threadIdx.x;         // 0..255, float4 index into D

    // --- softmax weights (unnormalized exp; 1/sum folded into final scale) ---
    float w[LAYERS];
    float m = -3.402823e38f;
#pragma unroll
    for (int l = 0; l < LAYERS; ++l) {
        w[l] = layer_w[l];
        m = fmaxf(m, w[l]);
    }
    float s = 0.f;
#pragma unroll
    for (int l = 0; l < LAYERS; ++l) {
        w[l] = __expf(w[l] - m);
        s += w[l];
    }
    const float invs = 1.f / s;

    // --- segment membership for the 8 tokens of this word group ---
    const int t0 = 2 * j0;
    float sc[TPB];
#pragma unroll
    for (int k = 0; k < TPB; ++k) {
        const int j = j0 + (k >> 1);
        sc[k] = (word_ids[b * LL + t0 + k] == j) ? 1.f : 0.f;
    }

    // --- branch-free weighted reduction over layers, 8 tokens at once ---
    const int D4 = DD / 4;
    const f32x4* base =
        (const f32x4*)bpe + ((size_t)(b * LAYERS) * LL + (size_t)t0) * D4 + tid;
    const size_t lstride = (size_t)LL * D4;   // float4 stride between layers

    f32x4 acc[TPB];
#pragma unroll
    for (int k = 0; k < TPB; ++k) acc[k] = (f32x4)0.f;

#pragma unroll
    for (int l = 0; l < LAYERS; ++l) {
        const f32x4* pl = base + (size_t)l * lstride;
#pragma unroll
        for (int k = 0; k < TPB; ++k) {
            f32x4 x = pl[(size_t)k * D4];    // 8 independent 1KB/wave bursts
            acc[k] += w[l] * x;
        }
    }

    // --- epilogue: combine token pairs into words, scale, store ---
#pragma unroll
    for (int v = 0; v < WPB; ++v) {
        const float c = sc[2*v] + sc[2*v+1];
        const float r = invs / fmaxf(c, 1.f);
        f32x4 res = (sc[2*v] * r) * acc[2*v] + (sc[2*v+1] * r) * acc[2*v+1];
        f32x4* op = (f32x4*)out + ((size_t)b * WW + (size_t)(j0 + v)) * D4 + tid;
        __builtin_nontemporal_store(res, op);
    }
}

extern "C" void kernel_launch(void* const* d_in, const int* in_sizes, int n_in,
                              void* d_out, int out_size, void* d_ws, size_t ws_size,
                              hipStream_t stream) {
    const float* bpe      = (const float*)d_in[0];  // [16,13,512,1024]
    const float* layer_w  = (const float*)d_in[1];  // [13]
    const int*   word_ids = (const int*)d_in[2];    // [16,512]
    float* out = (float*)d_out;                     // [16,256,1024]

    dim3 grid(BB * GPB);  // 1024 blocks
    dim3 block(256);
    MorphologicalTagger_13657996001460_kernel<<<grid, block, 0, stream>>>(
        bpe, layer_w, word_ids, out);
}